// Round 9
// baseline (140.456 us; speedup 1.0000x reference)
//
#include <hip/hip_runtime.h>
#include <hip/hip_bf16.h>

typedef float f32x4 __attribute__((ext_vector_type(4)));
typedef short short8 __attribute__((ext_vector_type(8)));

#define NT    325
#define DKK   32
#define NSL   384                 // B*H*T
#define SLICE (NT*DKK)            // 10400
#define TOTE  (NSL*SLICE)         // per-output-tensor elements
#define NKT   21                  // ceil(325/16)
#define PADV  352                 // 11*32, padded m for PV
#define VGRAN (32 * (PADV/8))     // 1408 16B-granules in Vt
// 1/sqrt(32) * log2(e): scores in log2 domain, exp -> exp2f
#define SCALE2 0.25506372f

// XOR swizzle on short-index (byte bits 4..6).
__device__ __forceinline__ int swz(int sidx, int row) { return sidx ^ ((row & 7) << 3); }

// HW packed f32->bf16 pair convert.
__device__ __forceinline__ unsigned cvtpk(float lo, float hi) {
    unsigned r;
    asm("v_cvt_pk_bf16_f32 %0, %1, %2" : "=v"(r) : "v"(lo), "v"(hi));
    return r;
}
// split (x,y) -> bf16-hi packed word (returned) + bf16-lo packed word (Markidis)
__device__ __forceinline__ unsigned pk2_split(float x, float y, unsigned& lopk) {
    const unsigned hi = cvtpk(x, y);
    const float hx = __builtin_bit_cast(float, hi << 16);
    const float hy = __builtin_bit_cast(float, hi & 0xffff0000u);
    lopk = cvtpk(x - hx, y - hy);
    return hi;
}
// gfx950 register-file lane swaps (no LDS pipe).
// swap32: a's upper 32 lanes <-> b's lower 32 lanes.
// swap16: a's odd 16-lane rows <-> b's even 16-lane rows.
__device__ __forceinline__ void swap32(unsigned& a, unsigned& b) {
    asm("v_permlane32_swap_b32 %0, %1" : "+v"(a), "+v"(b));
}
__device__ __forceinline__ void swap16(unsigned& a, unsigned& b) {
    asm("v_permlane16_swap_b32 %0, %1" : "+v"(a), "+v"(b));
}

// P repack fully in registers: lane(c,g) holds S[q=c][m=16kt+4g+r] for kt_even (a0)
// and kt_odd (a1); PV A-frag needs P[q=c][m=chunk+8g+j]. With u,v,s,t = packed
// pairs, (swap32;swap16)(u,s) -> (w0=[u0,u2,s0,s2], w2=[u1,u3,s1,s3]); same for
// (v,t) -> (w1,w3). 4 permlanes replace the LDS round-trip.
__device__ __forceinline__ short8 repack(const f32x4& a0, const f32x4& a1, bool hasB) {
    unsigned u = cvtpk(a0[0], a0[1]);
    unsigned v = cvtpk(a0[2], a0[3]);
    unsigned s = hasB ? cvtpk(a1[0], a1[1]) : 0u;
    unsigned t = hasB ? cvtpk(a1[2], a1[3]) : 0u;
    swap32(u, s); swap16(u, s);
    swap32(v, t); swap16(v, t);
    uint4 w; w.x = u; w.y = v; w.z = s; w.w = t;
    return __builtin_bit_cast(short8, w);
}

template <bool SPLIT>
__device__ __forceinline__ void load_q(const float* qsrc, short8& qh, short8& ql) {
    const float4 qa = *(const float4*)qsrc;
    const float4 qb = *(const float4*)(qsrc + 4);
    uint4 h, l;
    if constexpr (SPLIT) {
        h.x = pk2_split(qa.x * SCALE2, qa.y * SCALE2, l.x);
        h.y = pk2_split(qa.z * SCALE2, qa.w * SCALE2, l.y);
        h.z = pk2_split(qb.x * SCALE2, qb.y * SCALE2, l.z);
        h.w = pk2_split(qb.z * SCALE2, qb.w * SCALE2, l.w);
        ql = __builtin_bit_cast(short8, l);
    } else {
        h.x = cvtpk(qa.x * SCALE2, qa.y * SCALE2);
        h.y = cvtpk(qa.z * SCALE2, qa.w * SCALE2);
        h.z = cvtpk(qb.x * SCALE2, qb.y * SCALE2);
        h.w = cvtpk(qb.z * SCALE2, qb.w * SCALE2);
    }
    qh = __builtin_bit_cast(short8, h);
}

// DUAL-TILE flash attention core. Wave wv: pass 0 = tiles (wv, wv+8) sharing all
// K/V fragment reads; pass 1 = single tile 16+wv (waves 0..4).
template <bool SPLIT>
__device__ __forceinline__ void process(
    const float* __restrict__ qp, size_t base, float* __restrict__ op,
    const unsigned short* Kb, const unsigned short* Kl, const unsigned short* Vt,
    int c, int g, int wv, int kswz)
{
    const f32x4 zero = {0.f, 0.f, 0.f, 0.f};

    for (int pass = 0; pass < 2; ++pass) {
        if (pass == 1 && wv >= NKT - 16) return;   // only waves 0..4 have a tail tile
        const bool dual = (pass == 0);
        const int qtA = dual ? wv : 16 + wv;
        const int qtB = wv + 8;

        short8 qhA, qlA, qhB, qlB;
        {
            int qr = qtA * 16 + c; if (qr > NT - 1) qr = NT - 1;
            load_q<SPLIT>(qp + base + (size_t)qr * DKK + g * 8, qhA, qlA);
        }
        if (dual) {
            const int qr = qtB * 16 + c;           // <= 255, always valid
            load_q<SPLIT>(qp + base + (size_t)qr * DKK + g * 8, qhB, qlB);
        }

        f32x4 oA0 = zero, oA1 = zero, oB0 = zero, oB1 = zero;
        float tsA = 0.f, tsB = 0.f, mA = -1e30f, mB = -1e30f;

        #pragma unroll
        for (int ks = 0; ks < 11; ++ks) {
            const int fi0 = (((2 * ks) * 16 + c) * DKK + g * 8) ^ kswz;
            const int fi1 = fi0 + 16 * DKK;        // +512 shorts: swizzle bits untouched
            const bool hasB1 = (ks < 10);
            f32x4 aA0, aA1, aB0, aB1;

            __builtin_amdgcn_s_setprio(1);
            if constexpr (SPLIT) {
                const short8 kh0 = *(const short8*)&Kb[fi0];
                const short8 kl0 = *(const short8*)&Kl[fi0];
                { f32x4 t = __builtin_amdgcn_mfma_f32_16x16x32_bf16(kh0, qlA, zero, 0, 0, 0);
                  t = __builtin_amdgcn_mfma_f32_16x16x32_bf16(kl0, qhA, t, 0, 0, 0);
                  aA0 = __builtin_amdgcn_mfma_f32_16x16x32_bf16(kh0, qhA, t, 0, 0, 0); }
                if (dual) {
                  f32x4 t = __builtin_amdgcn_mfma_f32_16x16x32_bf16(kh0, qlB, zero, 0, 0, 0);
                  t = __builtin_amdgcn_mfma_f32_16x16x32_bf16(kl0, qhB, t, 0, 0, 0);
                  aB0 = __builtin_amdgcn_mfma_f32_16x16x32_bf16(kh0, qhB, t, 0, 0, 0); }
                if (hasB1) {
                    const short8 kh1 = *(const short8*)&Kb[fi1];
                    const short8 kl1 = *(const short8*)&Kl[fi1];
                    { f32x4 t = __builtin_amdgcn_mfma_f32_16x16x32_bf16(kh1, qlA, zero, 0, 0, 0);
                      t = __builtin_amdgcn_mfma_f32_16x16x32_bf16(kl1, qhA, t, 0, 0, 0);
                      aA1 = __builtin_amdgcn_mfma_f32_16x16x32_bf16(kh1, qhA, t, 0, 0, 0); }
                    if (dual) {
                      f32x4 t = __builtin_amdgcn_mfma_f32_16x16x32_bf16(kh1, qlB, zero, 0, 0, 0);
                      t = __builtin_amdgcn_mfma_f32_16x16x32_bf16(kl1, qhB, t, 0, 0, 0);
                      aB1 = __builtin_amdgcn_mfma_f32_16x16x32_bf16(kh1, qhB, t, 0, 0, 0); }
                }
            } else {
                const short8 k0 = *(const short8*)&Kb[fi0];
                aA0 = __builtin_amdgcn_mfma_f32_16x16x32_bf16(k0, qhA, zero, 0, 0, 0);
                if (dual) aB0 = __builtin_amdgcn_mfma_f32_16x16x32_bf16(k0, qhB, zero, 0, 0, 0);
                if (hasB1) {
                    const short8 k1 = *(const short8*)&Kb[fi1];
                    aA1 = __builtin_amdgcn_mfma_f32_16x16x32_bf16(k1, qhA, zero, 0, 0, 0);
                    if (dual) aB1 = __builtin_amdgcn_mfma_f32_16x16x32_bf16(k1, qhB, zero, 0, 0, 0);
                }
            }
            __builtin_amdgcn_s_setprio(0);

            if (ks == 10) {   // mask m >= 325 (tile 20: m = 320 + 4g + r)
                #pragma unroll
                for (int r = 0; r < 4; ++r) {
                    aA0[r] = (4 * g + r > 4) ? -1e30f : aA0[r];
                    if (dual) aB0[r] = (4 * g + r > 4) ? -1e30f : aB0[r];
                }
            }

            if constexpr (SPLIT) {
                // online max + wave-uniform defer-skip, per tile
                {
                    float pm = fmaxf(fmaxf(aA0[0], aA0[1]), fmaxf(aA0[2], aA0[3]));
                    if (hasB1) pm = fmaxf(pm, fmaxf(fmaxf(aA1[0], aA1[1]), fmaxf(aA1[2], aA1[3])));
                    pm = fmaxf(pm, __shfl_xor(pm, 16));
                    pm = fmaxf(pm, __shfl_xor(pm, 32));
                    if (__any(pm > mA)) {
                        const float mn = fmaxf(mA, pm);
                        const float f = exp2f(mA - mn);
                        mA = mn; tsA *= f;
                        #pragma unroll
                        for (int r = 0; r < 4; ++r) {
                            const float fr = __shfl(f, 4 * g + r);
                            oA0[r] *= fr; oA1[r] *= fr;
                        }
                    }
                    #pragma unroll
                    for (int r = 0; r < 4; ++r) aA0[r] = exp2f(aA0[r] - mA);
                    tsA += (aA0[0] + aA0[1]) + (aA0[2] + aA0[3]);
                    if (hasB1) {
                        #pragma unroll
                        for (int r = 0; r < 4; ++r) aA1[r] = exp2f(aA1[r] - mA);
                        tsA += (aA1[0] + aA1[1]) + (aA1[2] + aA1[3]);
                    }
                }
                if (dual) {
                    float pm = fmaxf(fmaxf(aB0[0], aB0[1]), fmaxf(aB0[2], aB0[3]));
                    if (hasB1) pm = fmaxf(pm, fmaxf(fmaxf(aB1[0], aB1[1]), fmaxf(aB1[2], aB1[3])));
                    pm = fmaxf(pm, __shfl_xor(pm, 16));
                    pm = fmaxf(pm, __shfl_xor(pm, 32));
                    if (__any(pm > mB)) {
                        const float mn = fmaxf(mB, pm);
                        const float f = exp2f(mB - mn);
                        mB = mn; tsB *= f;
                        #pragma unroll
                        for (int r = 0; r < 4; ++r) {
                            const float fr = __shfl(f, 4 * g + r);
                            oB0[r] *= fr; oB1[r] *= fr;
                        }
                    }
                    #pragma unroll
                    for (int r = 0; r < 4; ++r) aB0[r] = exp2f(aB0[r] - mB);
                    tsB += (aB0[0] + aB0[1]) + (aB0[2] + aB0[3]);
                    if (hasB1) {
                        #pragma unroll
                        for (int r = 0; r < 4; ++r) aB1[r] = exp2f(aB1[r] - mB);
                        tsB += (aB1[0] + aB1[1]) + (aB1[2] + aB1[3]);
                    }
                }
            } else {
                // |s| <= ~9 in log2 domain: no max subtraction needed
                #pragma unroll
                for (int r = 0; r < 4; ++r) aA0[r] = exp2f(aA0[r]);
                tsA += (aA0[0] + aA0[1]) + (aA0[2] + aA0[3]);
                if (hasB1) {
                    #pragma unroll
                    for (int r = 0; r < 4; ++r) aA1[r] = exp2f(aA1[r]);
                    tsA += (aA1[0] + aA1[1]) + (aA1[2] + aA1[3]);
                }
                if (dual) {
                    #pragma unroll
                    for (int r = 0; r < 4; ++r) aB0[r] = exp2f(aB0[r]);
                    tsB += (aB0[0] + aB0[1]) + (aB0[2] + aB0[3]);
                    if (hasB1) {
                        #pragma unroll
                        for (int r = 0; r < 4; ++r) aB1[r] = exp2f(aB1[r]);
                        tsB += (aB1[0] + aB1[1]) + (aB1[2] + aB1[3]);
                    }
                }
            }

            // shared V fragments; PV via in-register repack
            const short8 v0 = *(const short8*)&Vt[( c        * PADV + ks * 32 + g * 8) ^ kswz];
            const short8 v1 = *(const short8*)&Vt[((c + 16)  * PADV + ks * 32 + g * 8) ^ kswz];
            {
                const short8 af = repack(aA0, hasB1 ? aA1 : aA0, hasB1);
                __builtin_amdgcn_s_setprio(1);
                oA0 = __builtin_amdgcn_mfma_f32_16x16x32_bf16(af, v0, oA0, 0, 0, 0);
                oA1 = __builtin_amdgcn_mfma_f32_16x16x32_bf16(af, v1, oA1, 0, 0, 0);
                __builtin_amdgcn_s_setprio(0);
            }
            if (dual) {
                const short8 af = repack(aB0, hasB1 ? aB1 : aB0, hasB1);
                __builtin_amdgcn_s_setprio(1);
                oB0 = __builtin_amdgcn_mfma_f32_16x16x32_bf16(af, v0, oB0, 0, 0, 0);
                oB1 = __builtin_amdgcn_mfma_f32_16x16x32_bf16(af, v1, oB1, 0, 0, 0);
                __builtin_amdgcn_s_setprio(0);
            }
        }

        // finalize + store
        {
            float ts = tsA;
            ts += __shfl_xor(ts, 16);
            ts += __shfl_xor(ts, 32);
            const float inv = 1.0f / ts;
            #pragma unroll
            for (int r = 0; r < 4; ++r) {
                const int row = qtA * 16 + 4 * g + r;
                const float iv = __shfl(inv, 4 * g + r);
                if (row < NT) {
                    op[(size_t)row * DKK + c]      = oA0[r] * iv;
                    op[(size_t)row * DKK + c + 16] = oA1[r] * iv;
                }
            }
        }
        if (dual) {
            float ts = tsB;
            ts += __shfl_xor(ts, 16);
            ts += __shfl_xor(ts, 32);
            const float inv = 1.0f / ts;
            #pragma unroll
            for (int r = 0; r < 4; ++r) {
                const int row = qtB * 16 + 4 * g + r;   // always < 256 < NT
                const float iv = __shfl(inv, 4 * g + r);
                op[(size_t)row * DKK + c]      = oB0[r] * iv;
                op[(size_t)row * DKK + c + 16] = oB1[r] * iv;
            }
        }
    }
}

__global__ __launch_bounds__(512, 4)
void attn4_mfma(const float* __restrict__ Qf, const float* __restrict__ Kf,
                const float* __restrict__ Vf, const float* __restrict__ Qs,
                const float* __restrict__ Ks, const float* __restrict__ Vs,
                const float* __restrict__ Kj, const float* __restrict__ Vfp,
                float* __restrict__ out)
{
    __shared__ __align__(16) unsigned short Kb[336 * DKK];   // [m][d] bf16 hi (swizzled)
    __shared__ __align__(16) unsigned short Kl[336 * DKK];   // [m][d] bf16 lo (var==1)
    __shared__ __align__(16) unsigned short Vt[DKK * PADV];  // [d][m] bf16 (swizzled)

    const int tid = threadIdx.x;
    const int bid = blockIdx.x;
    const int g8  = bid >> 3, xx = bid & 7;
    const int var = (xx + g8) & 3;            // round-7 mapping: locality + XCD rotation
    const int bt  = 2 * g8 + (xx >> 2);
    const size_t base = (size_t)bt * SLICE;

    const float *qp, *kp, *vp;
    if      (var == 0) { qp = Qf; kp = Kf; vp = Vf; }
    else if (var == 1) { qp = Kf; kp = Qs; vp = Vf; }   // K = FlowSpeed(Qs)
    else if (var == 2) { qp = Ks; kp = Qf; vp = Vs; }
    else               { qp = Qs; kp = Ks; vp = Vs; }
    float* op = out + (size_t)var * TOTE + base;

    // ---- stage K -> Kb (bf16 hi) [+ Kl lo for var 1] ----
    for (int i8 = tid; i8 < SLICE / 8; i8 += 512) {
        const int idx = i8 * 8;
        const int m   = idx >> 5;
        const int sidx = swz(idx, m);
        const float* s = kp + base + idx;
        float4 a = *(const float4*)s;
        float4 b = *(const float4*)(s + 4);
        if (var == 1) {
            const float kj = Kj[m];
            const float rv = 1.0f / (Vfp[m] + 1e-5f);
            a.x = kj * (a.x - a.x * a.x * rv);
            a.y = kj * (a.y - a.y * a.y * rv);
            a.z = kj * (a.z - a.z * a.z * rv);
            a.w = kj * (a.w - a.w * a.w * rv);
            b.x = kj * (b.x - b.x * b.x * rv);
            b.y = kj * (b.y - b.y * b.y * rv);
            b.z = kj * (b.z - b.z * b.z * rv);
            b.w = kj * (b.w - b.w * b.w * rv);
            uint4 hw, lw;
            hw.x = pk2_split(a.x, a.y, lw.x);
            hw.y = pk2_split(a.z, a.w, lw.y);
            hw.z = pk2_split(b.x, b.y, lw.z);
            hw.w = pk2_split(b.z, b.w, lw.w);
            *(uint4*)&Kb[sidx] = hw;
            *(uint4*)&Kl[sidx] = lw;
        } else {
            uint4 pkv;
            pkv.x = cvtpk(a.x, a.y); pkv.y = cvtpk(a.z, a.w);
            pkv.z = cvtpk(b.x, b.y); pkv.w = cvtpk(b.z, b.w);
            *(uint4*)&Kb[sidx] = pkv;
        }
    }

    // ---- stage V -> Vt (bf16, transposed, zero-padded, swizzled) ----
    for (int gi = tid; gi < VGRAN; gi += 512) {
        const int dd = gi / 44;
        const int m8 = gi - dd * 44;
        const int mb = m8 * 8;
        float v[8];
        #pragma unroll
        for (int i = 0; i < 8; ++i) {
            const int m = mb + i;
            v[i] = (m < NT) ? vp[base + (size_t)m * DKK + dd] : 0.0f;
        }
        uint4 pkv;
        pkv.x = cvtpk(v[0], v[1]); pkv.y = cvtpk(v[2], v[3]);
        pkv.z = cvtpk(v[4], v[5]); pkv.w = cvtpk(v[6], v[7]);
        *(uint4*)&Vt[swz(dd * PADV + mb, dd)] = pkv;
    }
    __syncthreads();

    const int lane = tid & 63;
    const int wv   = tid >> 6;                // 0..7
    const int c    = lane & 15;
    const int g    = lane >> 4;
    const int kswz = (c & 7) << 3;

    if (var == 1) process<true >(qp, base, op, Kb, Kl, Vt, c, g, wv, kswz);
    else          process<false>(qp, base, op, Kb, Kl, Vt, c, g, wv, kswz);
}

extern "C" void kernel_launch(void* const* d_in, const int* in_sizes, int n_in,
                              void* d_out, int out_size, void* d_ws, size_t ws_size,
                              hipStream_t stream) {
    const float* Qf  = (const float*)d_in[0];
    const float* Kf  = (const float*)d_in[1];
    const float* Vf  = (const float*)d_in[2];
    const float* Qs  = (const float*)d_in[3];
    const float* Ks  = (const float*)d_in[4];
    const float* Vs  = (const float*)d_in[5];
    const float* Kj  = (const float*)d_in[6];
    const float* Vfp = (const float*)d_in[7];
    float* out = (float*)d_out;

    attn4_mfma<<<dim3(NSL * 4), dim3(512), 0, stream>>>(Qf, Kf, Vf, Qs, Ks, Vs, Kj, Vfp, out);
}